// Round 13
// baseline (445.100 us; speedup 1.0000x reference)
//
#include <hip/hip_runtime.h>
#include <hip/hip_bf16.h>

typedef unsigned short u16;
typedef unsigned char  u8;
typedef unsigned int   u32;
typedef unsigned long long u64;
typedef long long      i64;
using f32x4 = __attribute__((ext_vector_type(4))) float;
using i32x8 = __attribute__((ext_vector_type(8))) int;
using bf16x8 = __attribute__((ext_vector_type(8))) short;

#define EPSF 2.220446049250313e-16f
#define NS 4096      // samples
#define KP 6656      // padded K bytes: 128 ch * 52 (49 real + 3 zero-pad)
#define FSCALE 32.0f

#define GPTR(p) ((const __attribute__((address_space(1))) void*)(p))
#define LPTR(p) ((__attribute__((address_space(3))) void*)(p))

union frag8 { i32x8 v; i64 q[4]; };

__device__ __forceinline__ float bf2f(u16 u){
  union { unsigned i; float f; } x; x.i = ((unsigned)u) << 16; return x.f;
}
__device__ __forceinline__ u16 f2bf(float f){
  union { float f; unsigned u; } x; x.f = f;
  unsigned r = (x.u + 0x7FFFu + ((x.u >> 16) & 1u)) >> 16;   // RNE
  return (u16)r;
}

// ---------------- prep: indices, buckets (wave-aggregated), histogram, mask patches ----------------
// idx layout: [ix_t | iy_t | ix_r | iy_r], 4096 each. Exactly 8192 threads.
// TP/RP layout: [s][64] bf16, k=0..48 real, 49..63 zero-padded (MFMA K=64 epilogue).
__global__ __launch_bounds__(256) void k_prep(const float* __restrict__ tfld,
                                              const float* __restrict__ rfld,
                                              const float* __restrict__ mask,
                                              int* __restrict__ idx, int* __restrict__ H,
                                              int* __restrict__ cntT, int* __restrict__ bktT,
                                              int* __restrict__ cntR, int* __restrict__ bktR,
                                              u16* __restrict__ TP, u16* __restrict__ RP,
                                              float* __restrict__ ntp, float* __restrict__ nrp){
  int t = blockIdx.x * 256 + threadIdx.x;        // 0..8191, no stragglers
  int lane = threadIdx.x & 63;
  const float* f = (t < NS) ? tfld : rfld;
  int s = t & (NS - 1);
  int base = (t < NS) ? 0 : 2 * NS;
  float gx = (f[2*s]   + 1.0f) * 0.5f * 83.0f;
  float gy = (f[2*s+1] + 1.0f) * 0.5f * 83.0f;
  int ix = (int)fminf(fmaxf(rintf(gx), 0.0f), 83.0f);
  int iy = (int)fminf(fmaxf(rintf(gy), 0.0f), 83.0f);
  idx[base + s]      = ix;
  idx[base + NS + s] = iy;
  if (t >= NS) atomicAdd(&H[iy * 84 + ix], 1);

  // wave-aggregated bucket insert: one global atomic per wave per tile
  int tile = (iy / 28) * 3 + (ix / 28);
  int* cnt = (t < NS) ? cntT : cntR;             // wave-uniform (blocks don't straddle halves)
  int* bkt = (t < NS) ? bktT : bktR;
  u64 lt = (lane == 63) ? ~0ull >> 1 : ((1ull << (lane + 1)) - 1) >> 1;  // lanes < me
  for (int tt = 0; tt < 9; ++tt){
    u64 m = __ballot(tile == tt);
    if (m){
      int leader = __builtin_ctzll(m);
      int cbase = 0;
      if (lane == leader) cbase = atomicAdd(&cnt[tt], (int)__popcll(m));
      cbase = __shfl(cbase, leader);
      if (tile == tt) bkt[tt * 4096 + cbase + (int)__popcll(m & lt)] = s;
    }
  }

  // mask patch gather (s-major, bf16, K padded to 64) + exact fp32 squared norm
  u16*  P  = (t < NS) ? TP  : RP;
  float* np = (t < NS) ? ntp : nrp;
  u16* row = P + ((size_t)s << 6);
  int bx = ix * 3, by = iy * 3;
  float ss = 0.f;
  #pragma unroll
  for (int ki = 0; ki < 7; ++ki){
    #pragma unroll
    for (int kj = 0; kj < 7; ++kj){
      float v = mask[(by + ki) * 256 + (bx + kj)];
      row[ki * 7 + kj] = f2bf(v);
      ss += v * v;
    }
  }
  #pragma unroll
  for (int k = 49; k < 64; ++k) row[k] = 0;
  np[s] = ss;
}

// ---------------- per-channel mean, split into 3 row-bands ----------------
__global__ __launch_bounds__(256) void k_mean2(const float* __restrict__ refer,
                                               const int* __restrict__ H,
                                               float* __restrict__ ymean3){
  __shared__ int   Hs[28 * 84];
  __shared__ float part[4][49];
  int c = blockIdx.x, band = blockIdx.y;
  const float* plane = refer + ((size_t)c << 16);
  int ybase = band * 28;
  for (int p = threadIdx.x; p < 2352; p += 256) Hs[p] = H[ybase * 84 + p];
  __syncthreads();
  float acc[49];
  #pragma unroll
  for (int k = 0; k < 49; ++k) acc[k] = 0.f;
  for (int e = threadIdx.x; e < 2352; e += 256){
    int w = Hs[e];
    if (w){
      int y0 = ybase + e / 84, x0 = e % 84;
      float fw = (float)w;
      const float* pp = plane + (y0 * 3) * 256 + x0 * 3;
      #pragma unroll
      for (int ki = 0; ki < 7; ++ki)
        #pragma unroll
        for (int kj = 0; kj < 7; ++kj)
          acc[ki * 7 + kj] += fw * pp[ki * 256 + kj];
    }
  }
  int lane = threadIdx.x & 63, wid = threadIdx.x >> 6;
  #pragma unroll
  for (int k = 0; k < 49; ++k){
    float v = acc[k];
    #pragma unroll
    for (int o = 32; o > 0; o >>= 1) v += __shfl_down(v, o);
    if (lane == 0) part[wid][k] = v;
  }
  __syncthreads();
  for (int k = threadIdx.x; k < 49; k += 256)
    ymean3[(c * 3 + band) * 49 + k] =
      (part[0][k] + part[1][k] + part[2][k] + part[3][k]) * (1.0f / 4096.0f);
}

// ---------------- bucketed gather -> fp8 X (z dim selects target/refer) ----------------
// nsq2[(sel*NS + s)*128 + c] written exactly once per (sel,s,c) — no atomics.
__global__ __launch_bounds__(256) void k_gather(const float* __restrict__ tfeat,
                                                const float* __restrict__ rfeat,
                                                const int* __restrict__ idx,
                                                const int* __restrict__ cntT,
                                                const int* __restrict__ bktT,
                                                const int* __restrict__ cntR,
                                                const int* __restrict__ bktR,
                                                const float* __restrict__ ymean3,
                                                u8* __restrict__ Xt, u8* __restrict__ Xr,
                                                float* __restrict__ nsq2){
  __shared__ float R[88 * 92];
  __shared__ float ms[49];
  int sel = blockIdx.z;
  const float* feat = sel ? rfeat : tfeat;
  const int* ixv = idx + sel * 2 * NS;
  const int* iyv = ixv + NS;
  const int* cnt = sel ? cntR : cntT;
  const int* bkt = sel ? bktR : bktT;
  u8* X = sel ? Xr : Xt;
  float* nq2 = nsq2 + (size_t)sel * NS * 128;

  int c = blockIdx.x;      // 0..127
  int t = blockIdx.y;      // 0..8
  int ty = t / 3, tx = t % 3;
  const float* src = feat + ((size_t)c << 16) + (ty * 84) * 256 + tx * 84;
  for (int e = threadIdx.x; e < 88 * 22; e += 256){
    int r = e / 22, q = e % 22;
    *(f32x4*)&R[r * 92 + q * 4] = *(const f32x4*)(src + r * 256 + q * 4);
  }
  for (int k = threadIdx.x; k < 49; k += 256)
    ms[k] = ymean3[(c*3)*49 + k] + ymean3[(c*3+1)*49 + k] + ymean3[(c*3+2)*49 + k];
  __syncthreads();
  int n = cnt[t];
  const int* list = bkt + t * 4096;
  for (int e = threadIdx.x; e < n; e += 256){
    int s = list[e];
    int ly = iyv[s] * 3 - ty * 84;
    int lx = ixv[s] * 3 - tx * 84;
    u32* xr = (u32*)(X + (size_t)s * KP);
    int wbase = c * 13;
    int sw = (s & 1) << 1;
    float ss = 0.f;
    #pragma unroll
    for (int d = 0; d < 12; ++d){
      float v0 = R[(ly + (4*d+0)/7) * 92 + lx + (4*d+0)%7] - ms[4*d+0];
      float v1 = R[(ly + (4*d+1)/7) * 92 + lx + (4*d+1)%7] - ms[4*d+1];
      float v2 = R[(ly + (4*d+2)/7) * 92 + lx + (4*d+2)%7] - ms[4*d+2];
      float v3 = R[(ly + (4*d+3)/7) * 92 + lx + (4*d+3)%7] - ms[4*d+3];
      ss += v0*v0 + v1*v1 + v2*v2 + v3*v3;
      u32 dw = (u32)__builtin_amdgcn_cvt_pk_fp8_f32(v0 * FSCALE, v1 * FSCALE, 0, false);
      dw = (u32)__builtin_amdgcn_cvt_pk_fp8_f32(v2 * FSCALE, v3 * FSCALE, (int)dw, true);
      xr[(wbase + d) ^ sw] = dw;
    }
    float v = R[(ly + 6) * 92 + lx + 6] - ms[48];
    ss += v * v;
    xr[(wbase + 12) ^ sw] = (u32)__builtin_amdgcn_cvt_pk_fp8_f32(v * FSCALE, 0.0f, 0, false);
    nq2[(size_t)s * 128 + c] = ss;
  }
}

// ---------------- reciprocal norms: reduce nsq2 over 128 channels (coalesced f32x4) ----------------
__global__ void k_rnorm(const float* __restrict__ nsq2, float* __restrict__ rn){
  int i = blockIdx.x * 256 + threadIdx.x;
  if (i < 2 * NS){
    const f32x4* p = (const f32x4*)(nsq2 + (size_t)i * 128);
    f32x4 acc = {0.f, 0.f, 0.f, 0.f};
    #pragma unroll
    for (int q = 0; q < 32; ++q) acc += p[q];
    float ss = (acc[0] + acc[1]) + (acc[2] + acc[3]);
    rn[i] = (1.0f / FSCALE) / (sqrtf(ss) + EPSF);
  }
}

// ---------------- main GEMM (MX fp8, K=128 MFMA, scales=1.0) + fused d_prog epilogue ----------------
// 8-PHASE FINE-INTERLEAVE BUILD (R13): the 128x128/acc[4][4]/2-waves-per-SIMD
// loop plateaued at ~145 us across 5 schedule/occupancy variants (single-buf,
// dbuf, counted-vmcnt, 3-waves, 8-waves) — occupancy is NOT the limiter and
// coarse schedule splits are NOT the limiter. The un-tried lever is the
// per-phase {ds_read subtile || staging issue || MFMA cluster} interleave
// (learn_hip m196/m201: coarse splits neutral-to-worse, fine 8-phase +71%,
// 62% MfmaUtil at the SAME 2-waves/SIMD occupancy we run).
// Per K-tile, 4 phases: P0 reads all bf (16 b64) + af0, P1-P3 read af1-3;
// staging of the NEXT tile's 8 loads spread 3/3/2 over P0-P2; each phase:
// issue reads -> s_barrier -> lgkmcnt(0) -> setprio(1) -> 4 MFMA -> setprio(0)
// -> s_barrier. Tile end: vmcnt(0) (loads issued >=1-3 phases earlier, mostly
// landed) + barrier before buffer swap. setprio only pays in phase-split
// schedules (m218b; matches our R7 null). No sched_barrier (m141/m201).
// Hazards: reads of cur drain at each phase's lgkm0 before the tile-end
// barrier; nxt staging lands before next tile's P0 reads (vmcnt0+barrier).
// 8 uniform barriers/tile. Geometry/swizzles/epilogue bit-exact from R5.
// NOTE: no min-waves launch bound; (256,4) is container-fatal (R10/R11).
__global__ __launch_bounds__(256) void k_gemm(const u8* __restrict__ Xt,
                                              const u8* __restrict__ Xr,
                                              const u16* __restrict__ TP,
                                              const u16* __restrict__ RP,
                                              const float* __restrict__ ntp,
                                              const float* __restrict__ nrp,
                                              const float* __restrict__ rn,
                                              float* __restrict__ D){
  __shared__ u8 As[2][128 * 128];
  __shared__ u8 Bs[2][128 * 128];
  const int tid  = threadIdx.x;
  const int lane = tid & 63;
  const int w    = tid >> 6;
  const int wm   = w >> 1, wn = w & 1;
  const int b    = blockIdx.x;
  const int xcd  = b & 7, kb = b >> 3;
  const int i0 = ((xcd & 3) * 8 + (kb & 7)) * 128;
  const int j0 = ((xcd >> 2) * 16 + (kb >> 3)) * 128;

  const int srow = lane >> 3;              // 0..7
  const int cs   = lane & 7;               // LDS 16-B chunk
  const int g0   = cs ^ (srow >> 1);       // global chunk, even issues
  const int g1   = g0 ^ 4;                 // odd issues
  const u8* gae = Xt + (size_t)(i0 + w * 32 + srow) * KP + g0 * 16;
  const u8* gao = Xt + (size_t)(i0 + w * 32 + srow) * KP + g1 * 16;
  const u8* gbe = Xr + (size_t)(j0 + w * 32 + srow) * KP + g0 * 16;
  const u8* gbo = Xr + (size_t)(j0 + w * 32 + srow) * KP + g1 * 16;
  const int lofs = (w * 32) * 128;

  const int kg   = lane >> 4;              // 0..3 (K-group; also C/D row group)
  const int mrow = lane & 15;
  int offA[4], offB[4];
  #pragma unroll
  for (int j = 0; j < 4; ++j){
    offA[j] = (wm * 64 + mrow) * 128 + (((kg * 4 + j) ^ mrow) * 8);
    offB[j] = (wn * 64 + mrow) * 128 + (((kg * 4 + j) ^ mrow) * 8);
  }

  f32x4 acc[4][4] = {};

  // single staging issue (1024 B linear block ii of A or B) into buffer base lan/lbn
  auto ISSA = [&](u8* lan, int ii){
    const u8* pa = (ii & 1) ? gao : gae;
    __builtin_amdgcn_global_load_lds(GPTR(pa + ii * 8 * KP), LPTR(lan + ii * 1024), 16, 0, 0);
  };
  auto ISSB = [&](u8* lbn, int ii){
    const u8* pb = (ii & 1) ? gbo : gbe;
    __builtin_amdgcn_global_load_lds(GPTR(pb + ii * 8 * KP), LPTR(lbn + ii * 1024), 16, 0, 0);
  };

  // one K-tile, 4 phases; stages the NEXT tile into lan/lbn when pf
  auto TILE = [&](const u8* Ab, const u8* Bb, u8* lan, u8* lbn, bool pf){
    frag8 bf[4];
    frag8 af;
    // ---- phase 0: all bf + af0; stage 3 ----
    #pragma unroll
    for (int t = 0; t < 4; ++t)
      #pragma unroll
      for (int j = 0; j < 4; ++j)
        bf[t].q[j] = *(const i64*)(Bb + offB[j] + t * 2048);
    #pragma unroll
    for (int j = 0; j < 4; ++j) af.q[j] = *(const i64*)(Ab + offA[j]);
    if (pf){ ISSA(lan, 0); ISSB(lbn, 0); ISSA(lan, 1); }
    __builtin_amdgcn_s_barrier();
    asm volatile("s_waitcnt lgkmcnt(0)" ::: "memory");
    __builtin_amdgcn_s_setprio(1);
    #pragma unroll
    for (int bq = 0; bq < 4; ++bq)
      acc[0][bq] = __builtin_amdgcn_mfma_scale_f32_16x16x128_f8f6f4(
          af.v, bf[bq].v, acc[0][bq], 0, 0, 0, 127, 0, 127);
    __builtin_amdgcn_s_setprio(0);
    __builtin_amdgcn_s_barrier();
    // ---- phase 1: af1; stage 3 ----
    #pragma unroll
    for (int j = 0; j < 4; ++j) af.q[j] = *(const i64*)(Ab + offA[j] + 2048);
    if (pf){ ISSB(lbn, 1); ISSA(lan, 2); ISSB(lbn, 2); }
    __builtin_amdgcn_s_barrier();
    asm volatile("s_waitcnt lgkmcnt(0)" ::: "memory");
    __builtin_amdgcn_s_setprio(1);
    #pragma unroll
    for (int bq = 0; bq < 4; ++bq)
      acc[1][bq] = __builtin_amdgcn_mfma_scale_f32_16x16x128_f8f6f4(
          af.v, bf[bq].v, acc[1][bq], 0, 0, 0, 127, 0, 127);
    __builtin_amdgcn_s_setprio(0);
    __builtin_amdgcn_s_barrier();
    // ---- phase 2: af2; stage 2 + advance ----
    #pragma unroll
    for (int j = 0; j < 4; ++j) af.q[j] = *(const i64*)(Ab + offA[j] + 2 * 2048);
    if (pf){
      ISSA(lan, 3); ISSB(lbn, 3);
      gae += 128; gao += 128; gbe += 128; gbo += 128;
    }
    __builtin_amdgcn_s_barrier();
    asm volatile("s_waitcnt lgkmcnt(0)" ::: "memory");
    __builtin_amdgcn_s_setprio(1);
    #pragma unroll
    for (int bq = 0; bq < 4; ++bq)
      acc[2][bq] = __builtin_amdgcn_mfma_scale_f32_16x16x128_f8f6f4(
          af.v, bf[bq].v, acc[2][bq], 0, 0, 0, 127, 0, 127);
    __builtin_amdgcn_s_setprio(0);
    __builtin_amdgcn_s_barrier();
    // ---- phase 3: af3; tile-end vmcnt drain ----
    #pragma unroll
    for (int j = 0; j < 4; ++j) af.q[j] = *(const i64*)(Ab + offA[j] + 3 * 2048);
    __builtin_amdgcn_s_barrier();
    asm volatile("s_waitcnt lgkmcnt(0)" ::: "memory");
    __builtin_amdgcn_s_setprio(1);
    #pragma unroll
    for (int bq = 0; bq < 4; ++bq)
      acc[3][bq] = __builtin_amdgcn_mfma_scale_f32_16x16x128_f8f6f4(
          af.v, bf[bq].v, acc[3][bq], 0, 0, 0, 127, 0, 127);
    __builtin_amdgcn_s_setprio(0);
    if (pf) asm volatile("s_waitcnt vmcnt(0)" ::: "memory");
    __builtin_amdgcn_s_barrier();
  };

  // prologue: stage tile 0 fully into buf0 (latency exposed once)
  {
    u8* la0 = As[0] + lofs; u8* lb0 = Bs[0] + lofs;
    ISSA(la0, 0); ISSB(lb0, 0); ISSA(la0, 1); ISSB(lb0, 1);
    ISSA(la0, 2); ISSB(lb0, 2); ISSA(la0, 3); ISSB(lb0, 3);
    gae += 128; gao += 128; gbe += 128; gbo += 128;
    asm volatile("s_waitcnt vmcnt(0)" ::: "memory");
    __builtin_amdgcn_s_barrier();
  }

  for (int k2 = 0; k2 < 25; ++k2){                     // tiles 0..49
    TILE(As[0], Bs[0], As[1] + lofs, Bs[1] + lofs, true);
    TILE(As[1], Bs[1], As[0] + lofs, Bs[0] + lofs, true);
  }
  TILE(As[0], Bs[0], As[1] + lofs, Bs[1] + lofs, true);   // tile 50, stages 51
  TILE(As[1], Bs[1], As[0] + lofs, Bs[0] + lofs, false);  // tile 51 (no staging)

  // ---- epilogue: d_prog via bf16 MFMA (K=49 padded to 64), frags from global ----
  // A frag: row = lane&15, k = kg*8+e (+c*32)  — same pattern as the fp8 main loop.
  // B frag: col = lane&15, k = kg*8+e (+c*32).
  float rjv[4], nrpv[4];
  bf16x8 bfr[2][4];
  #pragma unroll
  for (int bq = 0; bq < 4; ++bq){
    int j = j0 + wn * 64 + bq * 16 + mrow;
    rjv[bq]  = rn[NS + j];
    nrpv[bq] = nrp[j];
    const u16* tp = TP + ((size_t)j << 6) + kg * 8;
    bfr[0][bq] = *(const bf16x8*)(tp);
    bfr[1][bq] = *(const bf16x8*)(tp + 32);
  }
  #pragma unroll
  for (int a = 0; a < 4; ++a){
    const u16* rp = RP + ((size_t)(i0 + wm * 64 + a * 16 + mrow) << 6) + kg * 8;
    bf16x8 af0 = *(const bf16x8*)(rp);
    bf16x8 af1 = *(const bf16x8*)(rp + 32);
    f32x4 dpa[4] = {};
    #pragma unroll
    for (int bq = 0; bq < 4; ++bq){
      dpa[bq] = __builtin_amdgcn_mfma_f32_16x16x32_bf16(af0, bfr[0][bq], dpa[bq], 0, 0, 0);
      dpa[bq] = __builtin_amdgcn_mfma_f32_16x16x32_bf16(af1, bfr[1][bq], dpa[bq], 0, 0, 0);
    }
    #pragma unroll
    for (int r = 0; r < 4; ++r){
      int i = i0 + wm * 64 + a * 16 + kg * 4 + r;
      float ni = ntp[i];
      float ri = rn[i];
      #pragma unroll
      for (int bq = 0; bq < 4; ++bq){
        int j = j0 + wn * 64 + bq * 16 + mrow;
        float dprog = fmaxf(nrpv[bq] + ni - 2.0f * dpa[bq][r], 0.0f) * (10.0f / 49.0f);
        float sim   = acc[a][bq][r] * ri * rjv[bq];
        float dcos  = fmaxf((1.0f - sim) * 0.5f, 0.0f);
        D[(size_t)i * NS + j] = dcos + dprog;
      }
    }
  }
}

// ---------------- per-row: min -> w=exp(2(1-d/dmin)) -> atomic -mean log(CX) ----------------
// Wave shfl reductions (order-invariant min; sum/max reorder stays within the
// nondeterminism envelope of the existing cross-block atomicAdd). 2 syncs total.
__global__ __launch_bounds__(256) void k_rowred(const float* __restrict__ D,
                                                float* __restrict__ out){
  int i = blockIdx.x, tid = threadIdx.x;
  int lane = tid & 63, wid = tid >> 6;
  const f32x4* row4 = (const f32x4*)(D + (size_t)i * NS);
  f32x4 v[4];
  float mn = 3.4e38f;
  #pragma unroll
  for (int t = 0; t < 4; ++t){
    v[t] = row4[tid + t * 256];
    #pragma unroll
    for (int q = 0; q < 4; ++q) mn = fminf(mn, v[t][q]);
  }
  __shared__ float wmin[4], wsum[4], wmax[4];
  #pragma unroll
  for (int o = 32; o > 0; o >>= 1) mn = fminf(mn, __shfl_xor(mn, o));
  if (lane == 0) wmin[wid] = mn;
  __syncthreads();
  float inv = 1.0f / (fminf(fminf(wmin[0], wmin[1]), fminf(wmin[2], wmin[3])) + EPSF);
  float sw = 0.f, mw = 0.f;
  #pragma unroll
  for (int t = 0; t < 4; ++t)
    #pragma unroll
    for (int q = 0; q < 4; ++q){
      float wv = expf((1.0f - v[t][q] * inv) * 2.0f);
      sw += wv; mw = fmaxf(mw, wv);
    }
  #pragma unroll
  for (int o = 32; o > 0; o >>= 1){
    sw += __shfl_xor(sw, o);
    mw = fmaxf(mw, __shfl_xor(mw, o));
  }
  if (lane == 0){ wsum[wid] = sw; wmax[wid] = mw; }
  __syncthreads();
  if (tid == 0){
    float S = (wsum[0] + wsum[1]) + (wsum[2] + wsum[3]);
    float M = fmaxf(fmaxf(wmax[0], wmax[1]), fmaxf(wmax[2], wmax[3]));
    atomicAdd(out, logf(M / S) * (-1.0f / 4096.0f));
  }
}

extern "C" void kernel_launch(void* const* d_in, const int* in_sizes, int n_in,
                              void* d_out, int out_size, void* d_ws, size_t ws_size,
                              hipStream_t stream){
  (void)in_sizes; (void)n_in; (void)out_size; (void)ws_size;
  const float* tfeat = (const float*)d_in[0];
  const float* rfeat = (const float*)d_in[1];
  const float* mask  = (const float*)d_in[2];
  const float* tfld  = (const float*)d_in[3];
  const float* rfld  = (const float*)d_in[4];

  char* p = (char*)d_ws;
  auto take = [&](size_t bytes) -> char* {
    char* r = p; p += (bytes + 255) & ~(size_t)255; return r;
  };
  int*   idx    = (int*)  take(4 * NS * sizeof(int));
  // ---- contiguous zero-region: H, cntT, cntR (single memset) ----
  int*   H      = (int*)  take(7056 * sizeof(int));
  int*   cntT   = (int*)  take(9 * sizeof(int));
  int*   cntR   = (int*)  take(9 * sizeof(int));
  size_t zspan  = (size_t)((char*)(cntR + 9) - (char*)H);
  // ---------------------------------------------------------------
  int*   bktT   = (int*)  take(9 * 4096 * sizeof(int));
  int*   bktR   = (int*)  take(9 * 4096 * sizeof(int));
  float* ymean3 = (float*)take(128 * 3 * 49 * sizeof(float));
  float* rn     = (float*)take(2 * NS * sizeof(float));
  float* ntp    = (float*)take(NS * sizeof(float));
  float* nrp    = (float*)take(NS * sizeof(float));
  float* nsq2   = (float*)take((size_t)2 * NS * 128 * sizeof(float));  // fully overwritten
  u16*   TP     = (u16*)  take((size_t)NS * 64 * sizeof(u16));
  u16*   RP     = (u16*)  take((size_t)NS * 64 * sizeof(u16));
  u8*    Xt     = (u8*)   take((size_t)NS * KP);
  u8*    Xr     = (u8*)   take((size_t)NS * KP);
  float* D      = (float*)take((size_t)NS * NS * sizeof(float));

  hipMemsetAsync(H, 0, zspan, stream);
  hipMemsetAsync(d_out, 0, sizeof(float), stream);
  k_prep<<<32, 256, 0, stream>>>(tfld, rfld, mask, idx, H, cntT, bktT, cntR, bktR,
                                 TP, RP, ntp, nrp);
  k_mean2<<<dim3(128, 3), 256, 0, stream>>>(rfeat, H, ymean3);
  k_gather<<<dim3(128, 9, 2), 256, 0, stream>>>(tfeat, rfeat, idx, cntT, bktT,
                                                cntR, bktR, ymean3, Xt, Xr, nsq2);
  k_rnorm<<<32, 256, 0, stream>>>(nsq2, rn);
  k_gemm<<<1024, 256, 0, stream>>>(Xt, Xr, TP, RP, ntp, nrp, rn, D);
  k_rowred<<<4096, 256, 0, stream>>>(D, (float*)d_out);
}

// Round 14
// 407.730 us; speedup vs baseline: 1.0917x; 1.0917x over previous
//
#include <hip/hip_runtime.h>
#include <hip/hip_bf16.h>

typedef unsigned short u16;
typedef unsigned char  u8;
typedef unsigned int   u32;
typedef unsigned long long u64;
typedef long long      i64;
using f32x4 = __attribute__((ext_vector_type(4))) float;
using i32x8 = __attribute__((ext_vector_type(8))) int;
using bf16x8 = __attribute__((ext_vector_type(8))) short;

#define EPSF 2.220446049250313e-16f
#define NS 4096      // samples
#define KP 6656      // padded K bytes: 128 ch * 52 (49 real + 3 zero-pad)
#define FSCALE 32.0f

#define GPTR(p) ((const __attribute__((address_space(1))) void*)(p))
#define LPTR(p) ((__attribute__((address_space(3))) void*)(p))

union frag8 { i32x8 v; i64 q[4]; };

__device__ __forceinline__ float bf2f(u16 u){
  union { unsigned i; float f; } x; x.i = ((unsigned)u) << 16; return x.f;
}
__device__ __forceinline__ u16 f2bf(float f){
  union { float f; unsigned u; } x; x.f = f;
  unsigned r = (x.u + 0x7FFFu + ((x.u >> 16) & 1u)) >> 16;   // RNE
  return (u16)r;
}

// ---------------- prep: indices, buckets (wave-aggregated), histogram, mask patches ----------------
// idx layout: [ix_t | iy_t | ix_r | iy_r], 4096 each. Exactly 8192 threads.
// TP/RP layout: [s][64] bf16, k=0..48 real, 49..63 zero-padded (MFMA K=64 epilogue).
__global__ __launch_bounds__(256) void k_prep(const float* __restrict__ tfld,
                                              const float* __restrict__ rfld,
                                              const float* __restrict__ mask,
                                              int* __restrict__ idx, int* __restrict__ H,
                                              int* __restrict__ cntT, int* __restrict__ bktT,
                                              int* __restrict__ cntR, int* __restrict__ bktR,
                                              u16* __restrict__ TP, u16* __restrict__ RP,
                                              float* __restrict__ ntp, float* __restrict__ nrp){
  int t = blockIdx.x * 256 + threadIdx.x;        // 0..8191, no stragglers
  int lane = threadIdx.x & 63;
  const float* f = (t < NS) ? tfld : rfld;
  int s = t & (NS - 1);
  int base = (t < NS) ? 0 : 2 * NS;
  float gx = (f[2*s]   + 1.0f) * 0.5f * 83.0f;
  float gy = (f[2*s+1] + 1.0f) * 0.5f * 83.0f;
  int ix = (int)fminf(fmaxf(rintf(gx), 0.0f), 83.0f);
  int iy = (int)fminf(fmaxf(rintf(gy), 0.0f), 83.0f);
  idx[base + s]      = ix;
  idx[base + NS + s] = iy;
  if (t >= NS) atomicAdd(&H[iy * 84 + ix], 1);

  // wave-aggregated bucket insert: one global atomic per wave per tile
  int tile = (iy / 28) * 3 + (ix / 28);
  int* cnt = (t < NS) ? cntT : cntR;             // wave-uniform (blocks don't straddle halves)
  int* bkt = (t < NS) ? bktT : bktR;
  u64 lt = (lane == 63) ? ~0ull >> 1 : ((1ull << (lane + 1)) - 1) >> 1;  // lanes < me
  for (int tt = 0; tt < 9; ++tt){
    u64 m = __ballot(tile == tt);
    if (m){
      int leader = __builtin_ctzll(m);
      int cbase = 0;
      if (lane == leader) cbase = atomicAdd(&cnt[tt], (int)__popcll(m));
      cbase = __shfl(cbase, leader);
      if (tile == tt) bkt[tt * 4096 + cbase + (int)__popcll(m & lt)] = s;
    }
  }

  // mask patch gather (s-major, bf16, K padded to 64) + exact fp32 squared norm
  u16*  P  = (t < NS) ? TP  : RP;
  float* np = (t < NS) ? ntp : nrp;
  u16* row = P + ((size_t)s << 6);
  int bx = ix * 3, by = iy * 3;
  float ss = 0.f;
  #pragma unroll
  for (int ki = 0; ki < 7; ++ki){
    #pragma unroll
    for (int kj = 0; kj < 7; ++kj){
      float v = mask[(by + ki) * 256 + (bx + kj)];
      row[ki * 7 + kj] = f2bf(v);
      ss += v * v;
    }
  }
  #pragma unroll
  for (int k = 49; k < 64; ++k) row[k] = 0;
  np[s] = ss;
}

// ---------------- per-channel mean, split into 3 row-bands ----------------
__global__ __launch_bounds__(256) void k_mean2(const float* __restrict__ refer,
                                               const int* __restrict__ H,
                                               float* __restrict__ ymean3){
  __shared__ int   Hs[28 * 84];
  __shared__ float part[4][49];
  int c = blockIdx.x, band = blockIdx.y;
  const float* plane = refer + ((size_t)c << 16);
  int ybase = band * 28;
  for (int p = threadIdx.x; p < 2352; p += 256) Hs[p] = H[ybase * 84 + p];
  __syncthreads();
  float acc[49];
  #pragma unroll
  for (int k = 0; k < 49; ++k) acc[k] = 0.f;
  for (int e = threadIdx.x; e < 2352; e += 256){
    int w = Hs[e];
    if (w){
      int y0 = ybase + e / 84, x0 = e % 84;
      float fw = (float)w;
      const float* pp = plane + (y0 * 3) * 256 + x0 * 3;
      #pragma unroll
      for (int ki = 0; ki < 7; ++ki)
        #pragma unroll
        for (int kj = 0; kj < 7; ++kj)
          acc[ki * 7 + kj] += fw * pp[ki * 256 + kj];
    }
  }
  int lane = threadIdx.x & 63, wid = threadIdx.x >> 6;
  #pragma unroll
  for (int k = 0; k < 49; ++k){
    float v = acc[k];
    #pragma unroll
    for (int o = 32; o > 0; o >>= 1) v += __shfl_down(v, o);
    if (lane == 0) part[wid][k] = v;
  }
  __syncthreads();
  for (int k = threadIdx.x; k < 49; k += 256)
    ymean3[(c * 3 + band) * 49 + k] =
      (part[0][k] + part[1][k] + part[2][k] + part[3][k]) * (1.0f / 4096.0f);
}

// ---------------- bucketed gather -> fp8 X (z dim selects target/refer) ----------------
// nsq2[(sel*NS + s)*128 + c] written exactly once per (sel,s,c) — no atomics.
__global__ __launch_bounds__(256) void k_gather(const float* __restrict__ tfeat,
                                                const float* __restrict__ rfeat,
                                                const int* __restrict__ idx,
                                                const int* __restrict__ cntT,
                                                const int* __restrict__ bktT,
                                                const int* __restrict__ cntR,
                                                const int* __restrict__ bktR,
                                                const float* __restrict__ ymean3,
                                                u8* __restrict__ Xt, u8* __restrict__ Xr,
                                                float* __restrict__ nsq2){
  __shared__ float R[88 * 92];
  __shared__ float ms[49];
  int sel = blockIdx.z;
  const float* feat = sel ? rfeat : tfeat;
  const int* ixv = idx + sel * 2 * NS;
  const int* iyv = ixv + NS;
  const int* cnt = sel ? cntR : cntT;
  const int* bkt = sel ? bktR : bktT;
  u8* X = sel ? Xr : Xt;
  float* nq2 = nsq2 + (size_t)sel * NS * 128;

  int c = blockIdx.x;      // 0..127
  int t = blockIdx.y;      // 0..8
  int ty = t / 3, tx = t % 3;
  const float* src = feat + ((size_t)c << 16) + (ty * 84) * 256 + tx * 84;
  for (int e = threadIdx.x; e < 88 * 22; e += 256){
    int r = e / 22, q = e % 22;
    *(f32x4*)&R[r * 92 + q * 4] = *(const f32x4*)(src + r * 256 + q * 4);
  }
  for (int k = threadIdx.x; k < 49; k += 256)
    ms[k] = ymean3[(c*3)*49 + k] + ymean3[(c*3+1)*49 + k] + ymean3[(c*3+2)*49 + k];
  __syncthreads();
  int n = cnt[t];
  const int* list = bkt + t * 4096;
  for (int e = threadIdx.x; e < n; e += 256){
    int s = list[e];
    int ly = iyv[s] * 3 - ty * 84;
    int lx = ixv[s] * 3 - tx * 84;
    u32* xr = (u32*)(X + (size_t)s * KP);
    int wbase = c * 13;
    int sw = (s & 1) << 1;
    float ss = 0.f;
    #pragma unroll
    for (int d = 0; d < 12; ++d){
      float v0 = R[(ly + (4*d+0)/7) * 92 + lx + (4*d+0)%7] - ms[4*d+0];
      float v1 = R[(ly + (4*d+1)/7) * 92 + lx + (4*d+1)%7] - ms[4*d+1];
      float v2 = R[(ly + (4*d+2)/7) * 92 + lx + (4*d+2)%7] - ms[4*d+2];
      float v3 = R[(ly + (4*d+3)/7) * 92 + lx + (4*d+3)%7] - ms[4*d+3];
      ss += v0*v0 + v1*v1 + v2*v2 + v3*v3;
      u32 dw = (u32)__builtin_amdgcn_cvt_pk_fp8_f32(v0 * FSCALE, v1 * FSCALE, 0, false);
      dw = (u32)__builtin_amdgcn_cvt_pk_fp8_f32(v2 * FSCALE, v3 * FSCALE, (int)dw, true);
      xr[(wbase + d) ^ sw] = dw;
    }
    float v = R[(ly + 6) * 92 + lx + 6] - ms[48];
    ss += v * v;
    xr[(wbase + 12) ^ sw] = (u32)__builtin_amdgcn_cvt_pk_fp8_f32(v * FSCALE, 0.0f, 0, false);
    nq2[(size_t)s * 128 + c] = ss;
  }
}

// ---------------- reciprocal norms: reduce nsq2 over 128 channels (coalesced f32x4) ----------------
__global__ void k_rnorm(const float* __restrict__ nsq2, float* __restrict__ rn){
  int i = blockIdx.x * 256 + threadIdx.x;
  if (i < 2 * NS){
    const f32x4* p = (const f32x4*)(nsq2 + (size_t)i * 128);
    f32x4 acc = {0.f, 0.f, 0.f, 0.f};
    #pragma unroll
    for (int q = 0; q < 32; ++q) acc += p[q];
    float ss = (acc[0] + acc[1]) + (acc[2] + acc[3]);
    rn[i] = (1.0f / FSCALE) / (sqrtf(ss) + EPSF);
  }
}

// ---------------- main GEMM (MX fp8, K=128 MFMA, scales=1.0) + fused d_prog epilogue ----------------
// CONSOLIDATION (R14): revert to the R5 build — the verified floor of the
// K-loop. Seven refcheck'd schedule/occupancy variants bracket it:
//   R1 single-buf 149 | R5 dbuf 145 | R7 counted-vmcnt 150 | R12 3-wave 177
//   R9 4-wave(spill) 153 | R8 big-tile 200 | R13 fine-phase 178 (+6.8M bank conflicts)
// => 128x128 tile / acc[4][4] / 2 waves/SIMD / simple dbuf is issue-bound at
// ~145 us in plain HIP; occupancy and coarse/fine scheduling are not levers
// at this decomposition (m201's 8-phase needs 8 waves x 16-MFMA phases — out
// of regime here, rule 23).
// 128x128 tile, BK=128 bytes, 52 K-iters, DOUBLE-BUFFERED, PEELED tail:
// STAGE(t+1) into idle buffer BEFORE compute of tile t; one __syncthreads per
// phase at the END (its vmcnt(0) waits on loads issued ~1300 cyc earlier).
// LDS: logical 8-B block b of row r at block b^(r&15) (conflict-free frag reads).
// Staging XOR (r>>1)&7 on 16-B chunks; X pre-permuted (dword w -> w^(2*(r&1))).
// Epilogue: d_prog dot (K=49 padded to 64) via bf16 MFMA from s-major TP/RP[s][64]
// (L2-resident, contiguous 16-B frags — no LDS, no barrier). bf16 C/D layout ==
// fp8 C/D layout, so dpa drops into the same write loop. D = dcos + dprog once.
// NOTE: no min-waves launch bound; (256,4) is container-fatal (R10/R11),
// (256,3) forces spills at this live-set (R6).
__global__ __launch_bounds__(256) void k_gemm(const u8* __restrict__ Xt,
                                              const u8* __restrict__ Xr,
                                              const u16* __restrict__ TP,
                                              const u16* __restrict__ RP,
                                              const float* __restrict__ ntp,
                                              const float* __restrict__ nrp,
                                              const float* __restrict__ rn,
                                              float* __restrict__ D){
  __shared__ u8 As[2][128 * 128];
  __shared__ u8 Bs[2][128 * 128];
  const int tid  = threadIdx.x;
  const int lane = tid & 63;
  const int w    = tid >> 6;
  const int wm   = w >> 1, wn = w & 1;
  const int b    = blockIdx.x;
  const int xcd  = b & 7, kb = b >> 3;
  const int i0 = ((xcd & 3) * 8 + (kb & 7)) * 128;
  const int j0 = ((xcd >> 2) * 16 + (kb >> 3)) * 128;

  const int srow = lane >> 3;              // 0..7
  const int cs   = lane & 7;               // LDS 16-B chunk
  const int g0   = cs ^ (srow >> 1);       // global chunk, even issues
  const int g1   = g0 ^ 4;                 // odd issues
  const u8* gae = Xt + (size_t)(i0 + w * 32 + srow) * KP + g0 * 16;
  const u8* gao = Xt + (size_t)(i0 + w * 32 + srow) * KP + g1 * 16;
  const u8* gbe = Xr + (size_t)(j0 + w * 32 + srow) * KP + g0 * 16;
  const u8* gbo = Xr + (size_t)(j0 + w * 32 + srow) * KP + g1 * 16;
  const int lofs = (w * 32) * 128;

  const int kg   = lane >> 4;              // 0..3 (K-group; also C/D row group)
  const int mrow = lane & 15;
  int offA[4], offB[4];
  #pragma unroll
  for (int j = 0; j < 4; ++j){
    offA[j] = (wm * 64 + mrow) * 128 + (((kg * 4 + j) ^ mrow) * 8);
    offB[j] = (wn * 64 + mrow) * 128 + (((kg * 4 + j) ^ mrow) * 8);
  }

  f32x4 acc[4][4] = {};

  // stage one 128B K-slab of A and B into the given buffer, advance global ptrs
  auto STAGE = [&](u8* lab, u8* lbb){
    #pragma unroll
    for (int ii = 0; ii < 4; ++ii){
      const u8* pa = (ii & 1) ? gao : gae;
      const u8* pb = (ii & 1) ? gbo : gbe;
      __builtin_amdgcn_global_load_lds(GPTR(pa + ii * 8 * KP), LPTR(lab + ii * 1024), 16, 0, 0);
      __builtin_amdgcn_global_load_lds(GPTR(pb + ii * 8 * KP), LPTR(lbb + ii * 1024), 16, 0, 0);
    }
    gae += 128; gao += 128; gbe += 128; gbo += 128;
  };

  auto COMPUTE = [&](const u8* Ab, const u8* Bb){
    frag8 bf[4];
    #pragma unroll
    for (int t = 0; t < 4; ++t)
      #pragma unroll
      for (int j = 0; j < 4; ++j)
        bf[t].q[j] = *(const i64*)(Bb + offB[j] + t * 2048);
    #pragma unroll
    for (int a = 0; a < 4; ++a){
      frag8 af;
      #pragma unroll
      for (int j = 0; j < 4; ++j)
        af.q[j] = *(const i64*)(Ab + offA[j] + a * 2048);
      #pragma unroll
      for (int bq = 0; bq < 4; ++bq)
        acc[a][bq] = __builtin_amdgcn_mfma_scale_f32_16x16x128_f8f6f4(
            af.v, bf[bq].v, acc[a][bq], 0, 0, 0, 127, 0, 127);
    }
  };

  // prologue: tile 0 into buf0 (latency exposed once)
  STAGE(As[0] + lofs, Bs[0] + lofs);
  __syncthreads();

  for (int kt2 = 0; kt2 < 25; ++kt2){      // tiles 0..49, branch-free body
    STAGE(As[1] + lofs, Bs[1] + lofs);     // tile 2k+1 -> buf1
    COMPUTE(As[0], Bs[0]);                 // tile 2k
    __syncthreads();                       // vmcnt(0): buf1 ready; lgkm: buf0 reads drained
    STAGE(As[0] + lofs, Bs[0] + lofs);     // tile 2k+2 -> buf0
    COMPUTE(As[1], Bs[1]);                 // tile 2k+1
    __syncthreads();
  }
  // peeled tail: tiles 50 (in buf0) and 51
  STAGE(As[1] + lofs, Bs[1] + lofs);       // tile 51 -> buf1
  COMPUTE(As[0], Bs[0]);                   // tile 50
  __syncthreads();
  COMPUTE(As[1], Bs[1]);                   // tile 51 (no further staging)

  // ---- epilogue: d_prog via bf16 MFMA (K=49 padded to 64), frags from global ----
  // A frag: row = lane&15, k = kg*8+e (+c*32)  — same pattern as the fp8 main loop.
  // B frag: col = lane&15, k = kg*8+e (+c*32).
  float rjv[4], nrpv[4];
  bf16x8 bfr[2][4];
  #pragma unroll
  for (int bq = 0; bq < 4; ++bq){
    int j = j0 + wn * 64 + bq * 16 + mrow;
    rjv[bq]  = rn[NS + j];
    nrpv[bq] = nrp[j];
    const u16* tp = TP + ((size_t)j << 6) + kg * 8;
    bfr[0][bq] = *(const bf16x8*)(tp);
    bfr[1][bq] = *(const bf16x8*)(tp + 32);
  }
  #pragma unroll
  for (int a = 0; a < 4; ++a){
    const u16* rp = RP + ((size_t)(i0 + wm * 64 + a * 16 + mrow) << 6) + kg * 8;
    bf16x8 af0 = *(const bf16x8*)(rp);
    bf16x8 af1 = *(const bf16x8*)(rp + 32);
    f32x4 dpa[4] = {};
    #pragma unroll
    for (int bq = 0; bq < 4; ++bq){
      dpa[bq] = __builtin_amdgcn_mfma_f32_16x16x32_bf16(af0, bfr[0][bq], dpa[bq], 0, 0, 0);
      dpa[bq] = __builtin_amdgcn_mfma_f32_16x16x32_bf16(af1, bfr[1][bq], dpa[bq], 0, 0, 0);
    }
    #pragma unroll
    for (int r = 0; r < 4; ++r){
      int i = i0 + wm * 64 + a * 16 + kg * 4 + r;
      float ni = ntp[i];
      float ri = rn[i];
      #pragma unroll
      for (int bq = 0; bq < 4; ++bq){
        int j = j0 + wn * 64 + bq * 16 + mrow;
        float dprog = fmaxf(nrpv[bq] + ni - 2.0f * dpa[bq][r], 0.0f) * (10.0f / 49.0f);
        float sim   = acc[a][bq][r] * ri * rjv[bq];
        float dcos  = fmaxf((1.0f - sim) * 0.5f, 0.0f);
        D[(size_t)i * NS + j] = dcos + dprog;
      }
    }
  }
}

// ---------------- per-row: min -> w=exp(2(1-d/dmin)) -> atomic -mean log(CX) ----------------
// Wave shfl reductions (order-invariant min; sum/max reorder stays within the
// nondeterminism envelope of the existing cross-block atomicAdd). 2 syncs total.
__global__ __launch_bounds__(256) void k_rowred(const float* __restrict__ D,
                                                float* __restrict__ out){
  int i = blockIdx.x, tid = threadIdx.x;
  int lane = tid & 63, wid = tid >> 6;
  const f32x4* row4 = (const f32x4*)(D + (size_t)i * NS);
  f32x4 v[4];
  float mn = 3.4e38f;
  #pragma unroll
  for (int t = 0; t < 4; ++t){
    v[t] = row4[tid + t * 256];
    #pragma unroll
    for (int q = 0; q < 4; ++q) mn = fminf(mn, v[t][q]);
  }
  __shared__ float wmin[4], wsum[4], wmax[4];
  #pragma unroll
  for (int o = 32; o > 0; o >>= 1) mn = fminf(mn, __shfl_xor(mn, o));
  if (lane == 0) wmin[wid] = mn;
  __syncthreads();
  float inv = 1.0f / (fminf(fminf(wmin[0], wmin[1]), fminf(wmin[2], wmin[3])) + EPSF);
  float sw = 0.f, mw = 0.f;
  #pragma unroll
  for (int t = 0; t < 4; ++t)
    #pragma unroll
    for (int q = 0; q < 4; ++q){
      float wv = expf((1.0f - v[t][q] * inv) * 2.0f);
      sw += wv; mw = fmaxf(mw, wv);
    }
  #pragma unroll
  for (int o = 32; o > 0; o >>= 1){
    sw += __shfl_xor(sw, o);
    mw = fmaxf(mw, __shfl_xor(mw, o));
  }
  if (lane == 0){ wsum[wid] = sw; wmax[wid] = mw; }
  __syncthreads();
  if (tid == 0){
    float S = (wsum[0] + wsum[1]) + (wsum[2] + wsum[3]);
    float M = fmaxf(fmaxf(wmax[0], wmax[1]), fmaxf(wmax[2], wmax[3]));
    atomicAdd(out, logf(M / S) * (-1.0f / 4096.0f));
  }
}

extern "C" void kernel_launch(void* const* d_in, const int* in_sizes, int n_in,
                              void* d_out, int out_size, void* d_ws, size_t ws_size,
                              hipStream_t stream){
  (void)in_sizes; (void)n_in; (void)out_size; (void)ws_size;
  const float* tfeat = (const float*)d_in[0];
  const float* rfeat = (const float*)d_in[1];
  const float* mask  = (const float*)d_in[2];
  const float* tfld  = (const float*)d_in[3];
  const float* rfld  = (const float*)d_in[4];

  char* p = (char*)d_ws;
  auto take = [&](size_t bytes) -> char* {
    char* r = p; p += (bytes + 255) & ~(size_t)255; return r;
  };
  int*   idx    = (int*)  take(4 * NS * sizeof(int));
  // ---- contiguous zero-region: H, cntT, cntR (single memset) ----
  int*   H      = (int*)  take(7056 * sizeof(int));
  int*   cntT   = (int*)  take(9 * sizeof(int));
  int*   cntR   = (int*)  take(9 * sizeof(int));
  size_t zspan  = (size_t)((char*)(cntR + 9) - (char*)H);
  // ---------------------------------------------------------------
  int*   bktT   = (int*)  take(9 * 4096 * sizeof(int));
  int*   bktR   = (int*)  take(9 * 4096 * sizeof(int));
  float* ymean3 = (float*)take(128 * 3 * 49 * sizeof(float));
  float* rn     = (float*)take(2 * NS * sizeof(float));
  float* ntp    = (float*)take(NS * sizeof(float));
  float* nrp    = (float*)take(NS * sizeof(float));
  float* nsq2   = (float*)take((size_t)2 * NS * 128 * sizeof(float));  // fully overwritten
  u16*   TP     = (u16*)  take((size_t)NS * 64 * sizeof(u16));
  u16*   RP     = (u16*)  take((size_t)NS * 64 * sizeof(u16));
  u8*    Xt     = (u8*)   take((size_t)NS * KP);
  u8*    Xr     = (u8*)   take((size_t)NS * KP);
  float* D      = (float*)take((size_t)NS * NS * sizeof(float));

  hipMemsetAsync(H, 0, zspan, stream);
  hipMemsetAsync(d_out, 0, sizeof(float), stream);
  k_prep<<<32, 256, 0, stream>>>(tfld, rfld, mask, idx, H, cntT, bktT, cntR, bktR,
                                 TP, RP, ntp, nrp);
  k_mean2<<<dim3(128, 3), 256, 0, stream>>>(rfeat, H, ymean3);
  k_gather<<<dim3(128, 9, 2), 256, 0, stream>>>(tfeat, rfeat, idx, cntT, bktT,
                                                cntR, bktR, ymean3, Xt, Xr, nsq2);
  k_rnorm<<<32, 256, 0, stream>>>(nsq2, rn);
  k_gemm<<<1024, 256, 0, stream>>>(Xt, Xr, TP, RP, ntp, nrp, rn, D);
  k_rowred<<<4096, 256, 0, stream>>>(D, (float*)d_out);
}

// Round 15
// 384.725 us; speedup vs baseline: 1.1569x; 1.0598x over previous
//
#include <hip/hip_runtime.h>
#include <hip/hip_bf16.h>

typedef unsigned short u16;
typedef unsigned char  u8;
typedef unsigned int   u32;
typedef unsigned long long u64;
typedef long long      i64;
using f32x4 = __attribute__((ext_vector_type(4))) float;
using i32x8 = __attribute__((ext_vector_type(8))) int;
using bf16x8 = __attribute__((ext_vector_type(8))) short;
using u32x4 = __attribute__((ext_vector_type(4))) u32;

#define EPSF 2.220446049250313e-16f
#define NS 4096      // samples
#define KP 6656      // padded K bytes: 128 ch * 52 (49 real + 3 zero-pad)
#define FSCALE 32.0f

#define GPTR(p) ((const __attribute__((address_space(1))) void*)(p))
#define LPTR(p) ((__attribute__((address_space(3))) void*)(p))

union frag8 { i32x8 v; i64 q[4]; };

__device__ __forceinline__ float bf2f(u16 u){
  union { unsigned i; float f; } x; x.i = ((unsigned)u) << 16; return x.f;
}
__device__ __forceinline__ u16 f2bf(float f){
  union { float f; unsigned u; } x; x.f = f;
  unsigned r = (x.u + 0x7FFFu + ((x.u >> 16) & 1u)) >> 16;   // RNE
  return (u16)r;
}

// ---------------- prep: indices, buckets (wave-aggregated), histogram, mask patches ----------------
// idx layout: [ix_t | iy_t | ix_r | iy_r], 4096 each. Exactly 8192 threads.
// TP/RP layout: [s][64] bf16, k=0..48 real, 49..63 zero-padded (MFMA K=64 epilogue).
__global__ __launch_bounds__(256) void k_prep(const float* __restrict__ tfld,
                                              const float* __restrict__ rfld,
                                              const float* __restrict__ mask,
                                              int* __restrict__ idx, int* __restrict__ H,
                                              int* __restrict__ cntT, int* __restrict__ bktT,
                                              int* __restrict__ cntR, int* __restrict__ bktR,
                                              u16* __restrict__ TP, u16* __restrict__ RP,
                                              float* __restrict__ ntp, float* __restrict__ nrp){
  int t = blockIdx.x * 256 + threadIdx.x;        // 0..8191, no stragglers
  int lane = threadIdx.x & 63;
  const float* f = (t < NS) ? tfld : rfld;
  int s = t & (NS - 1);
  int base = (t < NS) ? 0 : 2 * NS;
  float gx = (f[2*s]   + 1.0f) * 0.5f * 83.0f;
  float gy = (f[2*s+1] + 1.0f) * 0.5f * 83.0f;
  int ix = (int)fminf(fmaxf(rintf(gx), 0.0f), 83.0f);
  int iy = (int)fminf(fmaxf(rintf(gy), 0.0f), 83.0f);
  idx[base + s]      = ix;
  idx[base + NS + s] = iy;
  if (t >= NS) atomicAdd(&H[iy * 84 + ix], 1);

  // wave-aggregated bucket insert: one global atomic per wave per tile
  int tile = (iy / 28) * 3 + (ix / 28);
  int* cnt = (t < NS) ? cntT : cntR;             // wave-uniform (blocks don't straddle halves)
  int* bkt = (t < NS) ? bktT : bktR;
  u64 lt = (lane == 63) ? ~0ull >> 1 : ((1ull << (lane + 1)) - 1) >> 1;  // lanes < me
  for (int tt = 0; tt < 9; ++tt){
    u64 m = __ballot(tile == tt);
    if (m){
      int leader = __builtin_ctzll(m);
      int cbase = 0;
      if (lane == leader) cbase = atomicAdd(&cnt[tt], (int)__popcll(m));
      cbase = __shfl(cbase, leader);
      if (tile == tt) bkt[tt * 4096 + cbase + (int)__popcll(m & lt)] = s;
    }
  }

  // mask patch gather (s-major, bf16, K padded to 64) + exact fp32 squared norm
  u16*  P  = (t < NS) ? TP  : RP;
  float* np = (t < NS) ? ntp : nrp;
  u16* row = P + ((size_t)s << 6);
  int bx = ix * 3, by = iy * 3;
  float ss = 0.f;
  #pragma unroll
  for (int ki = 0; ki < 7; ++ki){
    #pragma unroll
    for (int kj = 0; kj < 7; ++kj){
      float v = mask[(by + ki) * 256 + (bx + kj)];
      row[ki * 7 + kj] = f2bf(v);
      ss += v * v;
    }
  }
  #pragma unroll
  for (int k = 49; k < 64; ++k) row[k] = 0;
  np[s] = ss;
}

// ---------------- per-channel mean, split into 3 row-bands ----------------
__global__ __launch_bounds__(256) void k_mean2(const float* __restrict__ refer,
                                               const int* __restrict__ H,
                                               float* __restrict__ ymean3){
  __shared__ int   Hs[28 * 84];
  __shared__ float part[4][49];
  int c = blockIdx.x, band = blockIdx.y;
  const float* plane = refer + ((size_t)c << 16);
  int ybase = band * 28;
  for (int p = threadIdx.x; p < 2352; p += 256) Hs[p] = H[ybase * 84 + p];
  __syncthreads();
  float acc[49];
  #pragma unroll
  for (int k = 0; k < 49; ++k) acc[k] = 0.f;
  for (int e = threadIdx.x; e < 2352; e += 256){
    int w = Hs[e];
    if (w){
      int y0 = ybase + e / 84, x0 = e % 84;
      float fw = (float)w;
      const float* pp = plane + (y0 * 3) * 256 + x0 * 3;
      #pragma unroll
      for (int ki = 0; ki < 7; ++ki)
        #pragma unroll
        for (int kj = 0; kj < 7; ++kj)
          acc[ki * 7 + kj] += fw * pp[ki * 256 + kj];
    }
  }
  int lane = threadIdx.x & 63, wid = threadIdx.x >> 6;
  #pragma unroll
  for (int k = 0; k < 49; ++k){
    float v = acc[k];
    #pragma unroll
    for (int o = 32; o > 0; o >>= 1) v += __shfl_down(v, o);
    if (lane == 0) part[wid][k] = v;
  }
  __syncthreads();
  for (int k = threadIdx.x; k < 49; k += 256)
    ymean3[(c * 3 + band) * 49 + k] =
      (part[0][k] + part[1][k] + part[2][k] + part[3][k]) * (1.0f / 4096.0f);
}

// ---------------- bucketed gather -> fp8 X (z dim selects target/refer) ----------------
// nsq2[(sel*NS + s)*128 + c] written exactly once per (sel,s,c) — no atomics.
// STORE WIDENING (R15): the 52-B output region per (s,c) is contiguous; the
// dword XOR (^sw, sw in {0,2}) permutes only WITHIN 16-B blocks. Buffer the 13
// dwords in registers, store fully-owned aligned blocks as dwordx4 (data
// pre-permuted via cndmask select — no runtime-indexed array, rule 20) and
// edges as singles. Alignment phase a = c&3 (13c mod 4 == c mod 4) is
// block-uniform -> uniform switch: a in {0,3}: 4 store instrs, {1,2}: 7.
// Avg 5.5 vs 13 -> scattered-store txns 13.6M -> 5.75M device-wide.
// Destinations and values identical to the old per-dword loop (same bijection).
__global__ __launch_bounds__(256) void k_gather(const float* __restrict__ tfeat,
                                                const float* __restrict__ rfeat,
                                                const int* __restrict__ idx,
                                                const int* __restrict__ cntT,
                                                const int* __restrict__ bktT,
                                                const int* __restrict__ cntR,
                                                const int* __restrict__ bktR,
                                                const float* __restrict__ ymean3,
                                                u8* __restrict__ Xt, u8* __restrict__ Xr,
                                                float* __restrict__ nsq2){
  __shared__ float R[88 * 92];
  __shared__ float ms[49];
  int sel = blockIdx.z;
  const float* feat = sel ? rfeat : tfeat;
  const int* ixv = idx + sel * 2 * NS;
  const int* iyv = ixv + NS;
  const int* cnt = sel ? cntR : cntT;
  const int* bkt = sel ? bktR : bktT;
  u8* X = sel ? Xr : Xt;
  float* nq2 = nsq2 + (size_t)sel * NS * 128;

  int c = blockIdx.x;      // 0..127
  int t = blockIdx.y;      // 0..8
  int ty = t / 3, tx = t % 3;
  const float* src = feat + ((size_t)c << 16) + (ty * 84) * 256 + tx * 84;
  for (int e = threadIdx.x; e < 88 * 22; e += 256){
    int r = e / 22, q = e % 22;
    *(f32x4*)&R[r * 92 + q * 4] = *(const f32x4*)(src + r * 256 + q * 4);
  }
  for (int k = threadIdx.x; k < 49; k += 256)
    ms[k] = ymean3[(c*3)*49 + k] + ymean3[(c*3+1)*49 + k] + ymean3[(c*3+2)*49 + k];
  __syncthreads();
  int n = cnt[t];
  const int* list = bkt + t * 4096;
  const int wbase = c * 13;
  const int ph = c & 3;                 // block-uniform alignment phase
  for (int e = threadIdx.x; e < n; e += 256){
    int s = list[e];
    int ly = iyv[s] * 3 - ty * 84;
    int lx = ixv[s] * 3 - tx * 84;
    u32* xr = (u32*)(X + (size_t)s * KP);
    int sw = (s & 1) << 1;
    bool odd = (s & 1);
    u32 v[13];
    float ss = 0.f;
    #pragma unroll
    for (int d = 0; d < 12; ++d){
      float v0 = R[(ly + (4*d+0)/7) * 92 + lx + (4*d+0)%7] - ms[4*d+0];
      float v1 = R[(ly + (4*d+1)/7) * 92 + lx + (4*d+1)%7] - ms[4*d+1];
      float v2 = R[(ly + (4*d+2)/7) * 92 + lx + (4*d+2)%7] - ms[4*d+2];
      float v3 = R[(ly + (4*d+3)/7) * 92 + lx + (4*d+3)%7] - ms[4*d+3];
      ss += v0*v0 + v1*v1 + v2*v2 + v3*v3;
      u32 dw = (u32)__builtin_amdgcn_cvt_pk_fp8_f32(v0 * FSCALE, v1 * FSCALE, 0, false);
      dw = (u32)__builtin_amdgcn_cvt_pk_fp8_f32(v2 * FSCALE, v3 * FSCALE, (int)dw, true);
      v[d] = dw;
    }
    {
      float vv = R[(ly + 6) * 92 + lx + 6] - ms[48];
      ss += vv * vv;
      v[12] = (u32)__builtin_amdgcn_cvt_pk_fp8_f32(vv * FSCALE, 0.0f, 0, false);
    }
    // widened stores: full 16-B blocks (data pre-permuted), edge dwords single
    auto BLK = [&](int o){              // block at dwords [wbase+o, wbase+o+3], (wbase+o)%4==0
      u32x4 d4;
      d4[0] = odd ? v[o+2] : v[o+0];
      d4[1] = odd ? v[o+3] : v[o+1];
      d4[2] = odd ? v[o+0] : v[o+2];
      d4[3] = odd ? v[o+1] : v[o+3];
      *(u32x4*)(xr + wbase + o) = d4;
    };
    auto SGL = [&](int d){ xr[(wbase + d) ^ sw] = v[d]; };
    switch (ph){
      case 0: BLK(0); BLK(4); BLK(8); SGL(12); break;
      case 1: SGL(0); SGL(1); SGL(2); BLK(3); BLK(7); SGL(11); SGL(12); break;
      case 2: SGL(0); SGL(1); BLK(2); BLK(6); SGL(10); SGL(11); SGL(12); break;
      case 3: SGL(0); BLK(1); BLK(5); BLK(9); break;
    }
    nq2[(size_t)s * 128 + c] = ss;
  }
}

// ---------------- reciprocal norms: reduce nsq2 over 128 channels (coalesced f32x4) ----------------
__global__ void k_rnorm(const float* __restrict__ nsq2, float* __restrict__ rn){
  int i = blockIdx.x * 256 + threadIdx.x;
  if (i < 2 * NS){
    const f32x4* p = (const f32x4*)(nsq2 + (size_t)i * 128);
    f32x4 acc = {0.f, 0.f, 0.f, 0.f};
    #pragma unroll
    for (int q = 0; q < 32; ++q) acc += p[q];
    float ss = (acc[0] + acc[1]) + (acc[2] + acc[3]);
    rn[i] = (1.0f / FSCALE) / (sqrtf(ss) + EPSF);
  }
}

// ---------------- main GEMM (MX fp8, K=128 MFMA, scales=1.0) + fused d_prog epilogue ----------------
// VERIFIED FLOOR (R14): 128x128 tile / acc[4][4] / 2 waves/SIMD / simple dbuf.
// Seven refcheck'd schedule/occupancy variants bracket it:
//   R1 single-buf 149 | R5/R14 dbuf 143-145 | R7 counted-vmcnt 150 | R12 3-wave 177
//   R9 4-wave(spill) 153 | R8 big-tile 200 | R13 fine-phase 178 (+6.8M bank conflicts)
// => issue-bound at ~145 us in plain HIP at this decomposition; occupancy and
// coarse/fine scheduling are not levers (m201's 8-phase needs 8 waves x 16-MFMA
// phases — out of regime here, rule 23).
// 128x128 tile, BK=128 bytes, 52 K-iters, DOUBLE-BUFFERED, PEELED tail:
// STAGE(t+1) into idle buffer BEFORE compute of tile t; one __syncthreads per
// phase at the END (its vmcnt(0) waits on loads issued ~1300 cyc earlier).
// LDS: logical 8-B block b of row r at block b^(r&15) (conflict-free frag reads).
// Staging XOR (r>>1)&7 on 16-B chunks; X pre-permuted (dword w -> w^(2*(r&1))).
// Epilogue: d_prog dot (K=49 padded to 64) via bf16 MFMA from s-major TP/RP[s][64]
// (L2-resident, contiguous 16-B frags — no LDS, no barrier). bf16 C/D layout ==
// fp8 C/D layout, so dpa drops into the same write loop. D = dcos + dprog once.
// NOTE: no min-waves launch bound; (256,4) is container-fatal (R10/R11),
// (256,3) forces spills at this live-set (R6).
__global__ __launch_bounds__(256) void k_gemm(const u8* __restrict__ Xt,
                                              const u8* __restrict__ Xr,
                                              const u16* __restrict__ TP,
                                              const u16* __restrict__ RP,
                                              const float* __restrict__ ntp,
                                              const float* __restrict__ nrp,
                                              const float* __restrict__ rn,
                                              float* __restrict__ D){
  __shared__ u8 As[2][128 * 128];
  __shared__ u8 Bs[2][128 * 128];
  const int tid  = threadIdx.x;
  const int lane = tid & 63;
  const int w    = tid >> 6;
  const int wm   = w >> 1, wn = w & 1;
  const int b    = blockIdx.x;
  const int xcd  = b & 7, kb = b >> 3;
  const int i0 = ((xcd & 3) * 8 + (kb & 7)) * 128;
  const int j0 = ((xcd >> 2) * 16 + (kb >> 3)) * 128;

  const int srow = lane >> 3;              // 0..7
  const int cs   = lane & 7;               // LDS 16-B chunk
  const int g0   = cs ^ (srow >> 1);       // global chunk, even issues
  const int g1   = g0 ^ 4;                 // odd issues
  const u8* gae = Xt + (size_t)(i0 + w * 32 + srow) * KP + g0 * 16;
  const u8* gao = Xt + (size_t)(i0 + w * 32 + srow) * KP + g1 * 16;
  const u8* gbe = Xr + (size_t)(j0 + w * 32 + srow) * KP + g0 * 16;
  const u8* gbo = Xr + (size_t)(j0 + w * 32 + srow) * KP + g1 * 16;
  const int lofs = (w * 32) * 128;

  const int kg   = lane >> 4;              // 0..3 (K-group; also C/D row group)
  const int mrow = lane & 15;
  int offA[4], offB[4];
  #pragma unroll
  for (int j = 0; j < 4; ++j){
    offA[j] = (wm * 64 + mrow) * 128 + (((kg * 4 + j) ^ mrow) * 8);
    offB[j] = (wn * 64 + mrow) * 128 + (((kg * 4 + j) ^ mrow) * 8);
  }

  f32x4 acc[4][4] = {};

  // stage one 128B K-slab of A and B into the given buffer, advance global ptrs
  auto STAGE = [&](u8* lab, u8* lbb){
    #pragma unroll
    for (int ii = 0; ii < 4; ++ii){
      const u8* pa = (ii & 1) ? gao : gae;
      const u8* pb = (ii & 1) ? gbo : gbe;
      __builtin_amdgcn_global_load_lds(GPTR(pa + ii * 8 * KP), LPTR(lab + ii * 1024), 16, 0, 0);
      __builtin_amdgcn_global_load_lds(GPTR(pb + ii * 8 * KP), LPTR(lbb + ii * 1024), 16, 0, 0);
    }
    gae += 128; gao += 128; gbe += 128; gbo += 128;
  };

  auto COMPUTE = [&](const u8* Ab, const u8* Bb){
    frag8 bf[4];
    #pragma unroll
    for (int t = 0; t < 4; ++t)
      #pragma unroll
      for (int j = 0; j < 4; ++j)
        bf[t].q[j] = *(const i64*)(Bb + offB[j] + t * 2048);
    #pragma unroll
    for (int a = 0; a < 4; ++a){
      frag8 af;
      #pragma unroll
      for (int j = 0; j < 4; ++j)
        af.q[j] = *(const i64*)(Ab + offA[j] + a * 2048);
      #pragma unroll
      for (int bq = 0; bq < 4; ++bq)
        acc[a][bq] = __builtin_amdgcn_mfma_scale_f32_16x16x128_f8f6f4(
            af.v, bf[bq].v, acc[a][bq], 0, 0, 0, 127, 0, 127);
    }
  };

  // prologue: tile 0 into buf0 (latency exposed once)
  STAGE(As[0] + lofs, Bs[0] + lofs);
  __syncthreads();

  for (int kt2 = 0; kt2 < 25; ++kt2){      // tiles 0..49, branch-free body
    STAGE(As[1] + lofs, Bs[1] + lofs);     // tile 2k+1 -> buf1
    COMPUTE(As[0], Bs[0]);                 // tile 2k
    __syncthreads();                       // vmcnt(0): buf1 ready; lgkm: buf0 reads drained
    STAGE(As[0] + lofs, Bs[0] + lofs);     // tile 2k+2 -> buf0
    COMPUTE(As[1], Bs[1]);                 // tile 2k+1
    __syncthreads();
  }
  // peeled tail: tiles 50 (in buf0) and 51
  STAGE(As[1] + lofs, Bs[1] + lofs);       // tile 51 -> buf1
  COMPUTE(As[0], Bs[0]);                   // tile 50
  __syncthreads();
  COMPUTE(As[1], Bs[1]);                   // tile 51 (no further staging)

  // ---- epilogue: d_prog via bf16 MFMA (K=49 padded to 64), frags from global ----
  // A frag: row = lane&15, k = kg*8+e (+c*32)  — same pattern as the fp8 main loop.
  // B frag: col = lane&15, k = kg*8+e (+c*32).
  float rjv[4], nrpv[4];
  bf16x8 bfr[2][4];
  #pragma unroll
  for (int bq = 0; bq < 4; ++bq){
    int j = j0 + wn * 64 + bq * 16 + mrow;
    rjv[bq]  = rn[NS + j];
    nrpv[bq] = nrp[j];
    const u16* tp = TP + ((size_t)j << 6) + kg * 8;
    bfr[0][bq] = *(const bf16x8*)(tp);
    bfr[1][bq] = *(const bf16x8*)(tp + 32);
  }
  #pragma unroll
  for (int a = 0; a < 4; ++a){
    const u16* rp = RP + ((size_t)(i0 + wm * 64 + a * 16 + mrow) << 6) + kg * 8;
    bf16x8 af0 = *(const bf16x8*)(rp);
    bf16x8 af1 = *(const bf16x8*)(rp + 32);
    f32x4 dpa[4] = {};
    #pragma unroll
    for (int bq = 0; bq < 4; ++bq){
      dpa[bq] = __builtin_amdgcn_mfma_f32_16x16x32_bf16(af0, bfr[0][bq], dpa[bq], 0, 0, 0);
      dpa[bq] = __builtin_amdgcn_mfma_f32_16x16x32_bf16(af1, bfr[1][bq], dpa[bq], 0, 0, 0);
    }
    #pragma unroll
    for (int r = 0; r < 4; ++r){
      int i = i0 + wm * 64 + a * 16 + kg * 4 + r;
      float ni = ntp[i];
      float ri = rn[i];
      #pragma unroll
      for (int bq = 0; bq < 4; ++bq){
        int j = j0 + wn * 64 + bq * 16 + mrow;
        float dprog = fmaxf(nrpv[bq] + ni - 2.0f * dpa[bq][r], 0.0f) * (10.0f / 49.0f);
        float sim   = acc[a][bq][r] * ri * rjv[bq];
        float dcos  = fmaxf((1.0f - sim) * 0.5f, 0.0f);
        D[(size_t)i * NS + j] = dcos + dprog;
      }
    }
  }
}

// ---------------- per-row: min -> w=exp(2(1-d/dmin)) -> atomic -mean log(CX) ----------------
// Wave shfl reductions (order-invariant min; sum/max reorder stays within the
// nondeterminism envelope of the existing cross-block atomicAdd). 2 syncs total.
__global__ __launch_bounds__(256) void k_rowred(const float* __restrict__ D,
                                                float* __restrict__ out){
  int i = blockIdx.x, tid = threadIdx.x;
  int lane = tid & 63, wid = tid >> 6;
  const f32x4* row4 = (const f32x4*)(D + (size_t)i * NS);
  f32x4 v[4];
  float mn = 3.4e38f;
  #pragma unroll
  for (int t = 0; t < 4; ++t){
    v[t] = row4[tid + t * 256];
    #pragma unroll
    for (int q = 0; q < 4; ++q) mn = fminf(mn, v[t][q]);
  }
  __shared__ float wmin[4], wsum[4], wmax[4];
  #pragma unroll
  for (int o = 32; o > 0; o >>= 1) mn = fminf(mn, __shfl_xor(mn, o));
  if (lane == 0) wmin[wid] = mn;
  __syncthreads();
  float inv = 1.0f / (fminf(fminf(wmin[0], wmin[1]), fminf(wmin[2], wmin[3])) + EPSF);
  float sw = 0.f, mw = 0.f;
  #pragma unroll
  for (int t = 0; t < 4; ++t)
    #pragma unroll
    for (int q = 0; q < 4; ++q){
      float wv = expf((1.0f - v[t][q] * inv) * 2.0f);
      sw += wv; mw = fmaxf(mw, wv);
    }
  #pragma unroll
  for (int o = 32; o > 0; o >>= 1){
    sw += __shfl_xor(sw, o);
    mw = fmaxf(mw, __shfl_xor(mw, o));
  }
  if (lane == 0){ wsum[wid] = sw; wmax[wid] = mw; }
  __syncthreads();
  if (tid == 0){
    float S = (wsum[0] + wsum[1]) + (wsum[2] + wsum[3]);
    float M = fmaxf(fmaxf(wmax[0], wmax[1]), fmaxf(wmax[2], wmax[3]));
    atomicAdd(out, logf(M / S) * (-1.0f / 4096.0f));
  }
}

extern "C" void kernel_launch(void* const* d_in, const int* in_sizes, int n_in,
                              void* d_out, int out_size, void* d_ws, size_t ws_size,
                              hipStream_t stream){
  (void)in_sizes; (void)n_in; (void)out_size; (void)ws_size;
  const float* tfeat = (const float*)d_in[0];
  const float* rfeat = (const float*)d_in[1];
  const float* mask  = (const float*)d_in[2];
  const float* tfld  = (const float*)d_in[3];
  const float* rfld  = (const float*)d_in[4];

  char* p = (char*)d_ws;
  auto take = [&](size_t bytes) -> char* {
    char* r = p; p += (bytes + 255) & ~(size_t)255; return r;
  };
  int*   idx    = (int*)  take(4 * NS * sizeof(int));
  // ---- contiguous zero-region: H, cntT, cntR (single memset) ----
  int*   H      = (int*)  take(7056 * sizeof(int));
  int*   cntT   = (int*)  take(9 * sizeof(int));
  int*   cntR   = (int*)  take(9 * sizeof(int));
  size_t zspan  = (size_t)((char*)(cntR + 9) - (char*)H);
  // ---------------------------------------------------------------
  int*   bktT   = (int*)  take(9 * 4096 * sizeof(int));
  int*   bktR   = (int*)  take(9 * 4096 * sizeof(int));
  float* ymean3 = (float*)take(128 * 3 * 49 * sizeof(float));
  float* rn     = (float*)take(2 * NS * sizeof(float));
  float* ntp    = (float*)take(NS * sizeof(float));
  float* nrp    = (float*)take(NS * sizeof(float));
  float* nsq2   = (float*)take((size_t)2 * NS * 128 * sizeof(float));  // fully overwritten
  u16*   TP     = (u16*)  take((size_t)NS * 64 * sizeof(u16));
  u16*   RP     = (u16*)  take((size_t)NS * 64 * sizeof(u16));
  u8*    Xt     = (u8*)   take((size_t)NS * KP);
  u8*    Xr     = (u8*)   take((size_t)NS * KP);
  float* D      = (float*)take((size_t)NS * NS * sizeof(float));

  hipMemsetAsync(H, 0, zspan, stream);
  hipMemsetAsync(d_out, 0, sizeof(float), stream);
  k_prep<<<32, 256, 0, stream>>>(tfld, rfld, mask, idx, H, cntT, bktT, cntR, bktR,
                                 TP, RP, ntp, nrp);
  k_mean2<<<dim3(128, 3), 256, 0, stream>>>(rfeat, H, ymean3);
  k_gather<<<dim3(128, 9, 2), 256, 0, stream>>>(tfeat, rfeat, idx, cntT, bktT,
                                                cntR, bktR, ymean3, Xt, Xr, nsq2);
  k_rnorm<<<32, 256, 0, stream>>>(nsq2, rn);
  k_gemm<<<1024, 256, 0, stream>>>(Xt, Xr, TP, RP, ntp, nrp, rn, D);
  k_rowred<<<4096, 256, 0, stream>>>(D, (float*)d_out);
}